// Round 5
// baseline (176.460 us; speedup 1.0000x reference)
//
#include <hip/hip_runtime.h>
#include <hip/hip_bf16.h>

#define NB 16
#define NN 512
#define ND 512
#define NH 8

using short8 = __attribute__((ext_vector_type(8))) short;
using f32x4  = __attribute__((ext_vector_type(4))) float;

static __device__ __forceinline__ unsigned short f2bf(float f) {
  unsigned u = __builtin_bit_cast(unsigned, f);
  unsigned r = 0x7fffu + ((u >> 16) & 1u);
  return (unsigned short)((u + r) >> 16);
}
static __device__ __forceinline__ float bf2f(unsigned short u) {
  return __builtin_bit_cast(float, (unsigned)u << 16);
}

// ---------------------------------------------------------------- kernel 0
// Transpose 4 weight mats [k][n] fp32 -> [n][k] bf16 (Wq,Wk,Wv,Wo)
__global__ __launch_bounds__(256) void wprep(
    const float* __restrict__ Wq, const float* __restrict__ Wk,
    const float* __restrict__ Wv, const float* __restrict__ Wo,
    unsigned short* __restrict__ T) {
  const float* W;
  switch (blockIdx.z) {
    case 0: W = Wq; break;
    case 1: W = Wk; break;
    case 2: W = Wv; break;
    default: W = Wo; break;
  }
  unsigned short* Wt = T + (size_t)blockIdx.z * 512 * 512;
  __shared__ float tile[64][65];
  const int t = threadIdx.x;
  const int k0 = blockIdx.x * 64, n0 = blockIdx.y * 64;
#pragma unroll
  for (int it = 0; it < 4; ++it) {
    int row = it * 16 + (t >> 4);
    int c4 = (t & 15) * 4;
    float4 v = *(const float4*)&W[(size_t)(k0 + row) * 512 + n0 + c4];
    tile[row][c4] = v.x; tile[row][c4 + 1] = v.y;
    tile[row][c4 + 2] = v.z; tile[row][c4 + 3] = v.w;
  }
  __syncthreads();
#pragma unroll
  for (int it = 0; it < 4; ++it) {
    int nr = it * 16 + (t >> 4);
    int k4 = (t & 15) * 4;
    ushort4 o;
    o.x = f2bf(tile[k4 + 0][nr]); o.y = f2bf(tile[k4 + 1][nr]);
    o.z = f2bf(tile[k4 + 2][nr]); o.w = f2bf(tile[k4 + 3][nr]);
    *(ushort4*)&Wt[(size_t)(n0 + nr) * 512 + k0 + k4] = o;
  }
}

// ---------------------------------------------------------------- kernel 1
// QKV projection: X[8192x512]fp32 @ Wt^T + b -> bf16, scattered to
// q_ws/k_ws [B,H,N,64], vt_ws [B,H,64,N]
__global__ __launch_bounds__(256) void qkv_gemm(
    const float* __restrict__ Xq, const float* __restrict__ Xk,
    const float* __restrict__ Xv, const unsigned short* __restrict__ Wt,
    const float* __restrict__ bq, const float* __restrict__ bk,
    const float* __restrict__ bv, unsigned short* __restrict__ q_ws,
    unsigned short* __restrict__ k_ws, unsigned short* __restrict__ vt_ws) {
  const int zi = blockIdx.z;
  const float* X = (zi == 0) ? Xq : (zi == 1) ? Xk : Xv;
  const unsigned short* Wz = Wt + (size_t)zi * 512 * 512;
  const float* bias = (zi == 0) ? bq : (zi == 1) ? bk : bv;
  const int m0 = blockIdx.x * 128, n0 = blockIdx.y * 128;
  __shared__ unsigned short Al[2][128][40];
  __shared__ unsigned short Bl[2][128][40];
  const int t = threadIdx.x;
  const int w = t >> 6, l = t & 63;
  const int lr = l & 15, lg = l >> 4;
  const int wr = (w >> 1) * 64, wc = (w & 1) * 64;
  f32x4 acc[4][4] = {};
  for (int kk = 0; kk < 512; kk += 64) {
    __syncthreads();
    {
      const int colk = (t & 15) * 4;
      const int kc = colk >> 5, kin = colk & 31;
#pragma unroll
      for (int p = 0; p < 8; ++p) {
        int row = p * 16 + (t >> 4);
        float4 v = *(const float4*)&X[(size_t)(m0 + row) * 512 + kk + colk];
        ushort4 o;
        o.x = f2bf(v.x); o.y = f2bf(v.y); o.z = f2bf(v.z); o.w = f2bf(v.w);
        *(ushort4*)&Al[kc][row][kin] = o;
      }
      const int colk8 = (t & 7) * 8;
      const int kc2 = colk8 >> 5, kin2 = colk8 & 31;
#pragma unroll
      for (int p = 0; p < 4; ++p) {
        int row = p * 32 + (t >> 3);
        short8 v = *(const short8*)&Wz[(size_t)(n0 + row) * 512 + kk + colk8];
        *(short8*)&Bl[kc2][row][kin2] = v;
      }
    }
    __syncthreads();
#pragma unroll
    for (int kc = 0; kc < 2; ++kc) {
      short8 a[4], b[4];
      const int lk = lg * 8;
#pragma unroll
      for (int i = 0; i < 4; ++i) a[i] = *(const short8*)&Al[kc][wr + i * 16 + lr][lk];
#pragma unroll
      for (int i = 0; i < 4; ++i) b[i] = *(const short8*)&Bl[kc][wc + i * 16 + lr][lk];
#pragma unroll
      for (int i = 0; i < 4; ++i)
#pragma unroll
        for (int j = 0; j < 4; ++j)
          acc[i][j] = __builtin_amdgcn_mfma_f32_16x16x32_bf16(a[i], b[j], acc[i][j], 0, 0, 0);
    }
  }
#pragma unroll
  for (int j = 0; j < 4; ++j) {
    const int col = n0 + wc + j * 16 + lr;
    const float bb = bias[col];
    const int hh = col >> 6, dv = col & 63;
#pragma unroll
    for (int i = 0; i < 4; ++i) {
      const int mbase = m0 + wr + i * 16 + lg * 4;
      const int b_ = mbase >> 9, nt = mbase & 511;
      if (zi == 2) {
        ushort4 o;
        o.x = f2bf(acc[i][j][0] + bb); o.y = f2bf(acc[i][j][1] + bb);
        o.z = f2bf(acc[i][j][2] + bb); o.w = f2bf(acc[i][j][3] + bb);
        *(ushort4*)&vt_ws[((size_t)(b_ * NH + hh) * 64 + dv) * 512 + nt] = o;
      } else {
        unsigned short* dst = (zi == 0) ? q_ws : k_ws;
#pragma unroll
        for (int r = 0; r < 4; ++r)
          dst[((size_t)(b_ * NH + hh) * 512 + nt + r) * 64 + dv] = f2bf(acc[i][j][r] + bb);
      }
    }
  }
}

// ---------------------------------------------------------------- kernel 2
// Attention v5 — occupancy-first redesign:
//   block = 16 q-rows (grid 32x128), 4 waves x 128 keys each.
//   e1 = box*exp(att*scale) (log eliminated algebraically), stored bf16 in
//   per-wave LDS tile immediately (no persistent z registers).
//   pass2 re-reads e1, P=exp(w_mn+Ext) stored unnormalized; PV output rows
//   scaled by 1/l2 in the epilogue.
//   launch_bounds(256,8): VGPR<=64 -> 8 waves/SIMD; LDS ~17.5KB -> 8 blk/CU.
__global__ __launch_bounds__(256, 8) void attn_kernel(
    const unsigned short* __restrict__ q_ws, const unsigned short* __restrict__ k_ws,
    const unsigned short* __restrict__ vt_ws, const float* __restrict__ box,
    const float* __restrict__ Ext, unsigned short* __restrict__ hidden) {
  const int t = threadIdx.x;
  const int w = t >> 6, l = t & 63;
  const int lr = l & 15, lg = l >> 4;
  const int bh = blockIdx.y;
  const int q0 = blockIdx.x * 16;
  const int b = bh >> 3, h = bh & 7;

  const unsigned short* Qp = q_ws + (size_t)bh * 512 * 64;
  const unsigned short* Kp = k_ws + (size_t)bh * 512 * 64;
  const unsigned short* Vt = vt_ws + (size_t)bh * 64 * 512;
  const float* boxp = box + ((size_t)bh * 512 + q0) * 512;
  const float* Ep = Ext + ((size_t)bh * 512 + q0) * 512;

  __shared__ float red[4][16];
  __shared__ float red2[4][16];
  // per-wave: e1/P bf16 [16][136] (4352B) == out f32 [16][68] (4352B)
  __shared__ __align__(16) unsigned char wsh[4][4352];

  const int n0w = w * 128;  // this wave's 128-key chunk
  unsigned short(*Pw)[136] = (unsigned short(*)[136])wsh[w];

  // Q fragments (B operand), rows q0+lr
  short8 qf0 = *(const short8*)&Qp[(size_t)(q0 + lr) * 64 + lg * 8];
  short8 qf1 = *(const short8*)&Qp[(size_t)(q0 + lr) * 64 + 32 + lg * 8];

  // ---- pass1: e1 = clip(box)*exp(att*scale); bf16 -> LDS; row sum ----
  // thread's elements: [q = q0+lr][k = n0w + c*16 + lg*4 + r]
  float s1 = 0.f;
#pragma unroll
  for (int c = 0; c < 8; ++c) {
    const int krow = n0w + c * 16 + lr;
    short8 kf0 = *(const short8*)&Kp[(size_t)krow * 64 + lg * 8];
    short8 kf1 = *(const short8*)&Kp[(size_t)krow * 64 + 32 + lg * 8];
    f32x4 bx4 = *(const f32x4*)&boxp[(size_t)lr * 512 + n0w + c * 16 + lg * 4];
    f32x4 a = {0.f, 0.f, 0.f, 0.f};
    a = __builtin_amdgcn_mfma_f32_16x16x32_bf16(kf0, qf0, a, 0, 0, 0);
    a = __builtin_amdgcn_mfma_f32_16x16x32_bf16(kf1, qf1, a, 0, 0, 0);
    ushort4 o;
    {
      float e0 = fmaxf(bx4[0], 1e-6f) * __expf(a[0] * 0.125f);
      float e1 = fmaxf(bx4[1], 1e-6f) * __expf(a[1] * 0.125f);
      float e2 = fmaxf(bx4[2], 1e-6f) * __expf(a[2] * 0.125f);
      float e3 = fmaxf(bx4[3], 1e-6f) * __expf(a[3] * 0.125f);
      s1 += (e0 + e1) + (e2 + e3);
      o.x = f2bf(e0); o.y = f2bf(e1); o.z = f2bf(e2); o.w = f2bf(e3);
    }
    *(ushort4*)&Pw[lr][c * 16 + lg * 4] = o;
  }
  s1 += __shfl_xor(s1, 16);
  s1 += __shfl_xor(s1, 32);
  if (lg == 0) red[w][lr] = s1;
  __syncthreads();
  const float l1i = 1.0f / (red[0][lr] + red[1][lr] + red[2][lr] + red[3][lr]);

  // ---- pass2: P = exp(e1*l1i + Ext), unnormalized bf16 back to LDS ----
  float s2 = 0.f;
#pragma unroll
  for (int c = 0; c < 8; ++c) {
    f32x4 ex4 = *(const f32x4*)&Ep[(size_t)lr * 512 + n0w + c * 16 + lg * 4];
    ushort4 u = *(const ushort4*)&Pw[lr][c * 16 + lg * 4];
    ushort4 o;
    {
      float e0 = __expf(bf2f(u.x) * l1i + ex4[0]);
      float e1 = __expf(bf2f(u.y) * l1i + ex4[1]);
      float e2 = __expf(bf2f(u.z) * l1i + ex4[2]);
      float e3 = __expf(bf2f(u.w) * l1i + ex4[3]);
      s2 += (e0 + e1) + (e2 + e3);
      o.x = f2bf(e0); o.y = f2bf(e1); o.z = f2bf(e2); o.w = f2bf(e3);
    }
    *(ushort4*)&Pw[lr][c * 16 + lg * 4] = o;
  }
  s2 += __shfl_xor(s2, 16);
  s2 += __shfl_xor(s2, 32);
  if (lg == 0) red2[w][lr] = s2;
  __syncthreads();

  // ---- PV: wave's partial over its 128 keys (P unnormalized) ----
  f32x4 o4[4] = {};
#pragma unroll
  for (int kc = 0; kc < 4; ++kc) {
    short8 pa = *(const short8*)&Pw[lr][kc * 32 + lg * 8];
#pragma unroll
    for (int c2 = 0; c2 < 4; ++c2) {
      short8 vf = *(const short8*)&Vt[(size_t)(c2 * 16 + lr) * 512 + n0w + kc * 32 + lg * 8];
      o4[c2] = __builtin_amdgcn_mfma_f32_16x16x32_bf16(pa, vf, o4[c2], 0, 0, 0);
    }
  }
  // l2 inverses for this thread's output rows (m = lg*4+r)
  f32x4 rs = *(const f32x4*)&red2[0][lg * 4];
#pragma unroll
  for (int w2 = 1; w2 < 4; ++w2) {
    f32x4 p = *(const f32x4*)&red2[w2][lg * 4];
#pragma unroll
    for (int r = 0; r < 4; ++r) rs[r] += p[r];
  }
  f32x4 l2v;
#pragma unroll
  for (int r = 0; r < 4; ++r) l2v[r] = 1.0f / rs[r];
  // partial out (normalized) -> own region (aliases P tile; own-wave only)
  float* ow = (float*)wsh[w];
#pragma unroll
  for (int c2 = 0; c2 < 4; ++c2)
#pragma unroll
    for (int r = 0; r < 4; ++r)
      ow[(lg * 4 + r) * 68 + c2 * 16 + lr] = o4[c2][r] * l2v[r];
  __syncthreads();
  // cross-wave sum + vectorized store (ushort4)
  {
    const int lrow = t >> 4;
    const int d4 = (t & 15) * 4;
    f32x4 s = *(const f32x4*)&((const float*)wsh[0])[lrow * 68 + d4];
#pragma unroll
    for (int w2 = 1; w2 < 4; ++w2) {
      f32x4 p = *(const f32x4*)&((const float*)wsh[w2])[lrow * 68 + d4];
#pragma unroll
      for (int r = 0; r < 4; ++r) s[r] += p[r];
    }
    ushort4 oo;
    oo.x = f2bf(s[0]); oo.y = f2bf(s[1]); oo.z = f2bf(s[2]); oo.w = f2bf(s[3]);
    *(ushort4*)&hidden[(size_t)(b * 512 + q0 + lrow) * 512 + h * 64 + d4] = oo;
  }
}

// ---------------------------------------------------------------- kernel 3
// out = hidden[8192x512]bf16 @ WoT + bo  (fp32 out)
__global__ __launch_bounds__(256) void out_gemm(
    const unsigned short* __restrict__ hidden, const unsigned short* __restrict__ WoT,
    const float* __restrict__ bo, float* __restrict__ out) {
  const int m0 = blockIdx.x * 128, n0 = blockIdx.y * 128;
  __shared__ unsigned short Al[2][128][40];
  __shared__ unsigned short Bl[2][128][40];
  const int t = threadIdx.x;
  const int w = t >> 6, l = t & 63;
  const int lr = l & 15, lg = l >> 4;
  const int wr = (w >> 1) * 64, wc = (w & 1) * 64;
  f32x4 acc[4][4] = {};
  for (int kk = 0; kk < 512; kk += 64) {
    __syncthreads();
    {
      const int colk8 = (t & 7) * 8;
      const int kc2 = colk8 >> 5, kin2 = colk8 & 31;
#pragma unroll
      for (int p = 0; p < 4; ++p) {
        int row = p * 32 + (t >> 3);
        short8 v = *(const short8*)&hidden[(size_t)(m0 + row) * 512 + kk + colk8];
        *(short8*)&Al[kc2][row][kin2] = v;
      }
#pragma unroll
      for (int p = 0; p < 4; ++p) {
        int row = p * 32 + (t >> 3);
        short8 v = *(const short8*)&WoT[(size_t)(n0 + row) * 512 + kk + colk8];
        *(short8*)&Bl[kc2][row][kin2] = v;
      }
    }
    __syncthreads();
#pragma unroll
    for (int kc = 0; kc < 2; ++kc) {
      short8 a[4], b[4];
      const int lk = lg * 8;
#pragma unroll
      for (int i = 0; i < 4; ++i) a[i] = *(const short8*)&Al[kc][wr + i * 16 + lr][lk];
#pragma unroll
      for (int i = 0; i < 4; ++i) b[i] = *(const short8*)&Bl[kc][wc + i * 16 + lr][lk];
#pragma unroll
      for (int i = 0; i < 4; ++i)
#pragma unroll
        for (int j = 0; j < 4; ++j)
          acc[i][j] = __builtin_amdgcn_mfma_f32_16x16x32_bf16(a[i], b[j], acc[i][j], 0, 0, 0);
    }
  }
#pragma unroll
  for (int j = 0; j < 4; ++j) {
    const int col = n0 + wc + j * 16 + lr;
    const float bb = bo[col];
#pragma unroll
    for (int i = 0; i < 4; ++i)
#pragma unroll
      for (int r = 0; r < 4; ++r)
        out[(size_t)(m0 + wr + i * 16 + lg * 4 + r) * 512 + col] = acc[i][j][r] + bb;
  }
}

// ---------------------------------------------------------------- launch
extern "C" void kernel_launch(void* const* d_in, const int* in_sizes, int n_in,
                              void* d_out, int out_size, void* d_ws, size_t ws_size,
                              hipStream_t stream) {
  const float* queries = (const float*)d_in[0];
  const float* keys = (const float*)d_in[1];
  const float* values = (const float*)d_in[2];
  const float* box = (const float*)d_in[3];
  const float* ext = (const float*)d_in[4];
  const float* Wq = (const float*)d_in[5];
  const float* bq = (const float*)d_in[6];
  const float* Wk = (const float*)d_in[7];
  const float* bk = (const float*)d_in[8];
  const float* Wv = (const float*)d_in[9];
  const float* bv = (const float*)d_in[10];
  const float* Wo = (const float*)d_in[11];
  const float* bo = (const float*)d_in[12];
  float* out = (float*)d_out;

  char* ws = (char*)d_ws;
  unsigned short* q_ws = (unsigned short*)(ws);
  unsigned short* k_ws = (unsigned short*)(ws + 8u * 1024 * 1024);
  unsigned short* vt_ws = (unsigned short*)(ws + 16u * 1024 * 1024);
  unsigned short* hidden = (unsigned short*)(ws + 24u * 1024 * 1024);
  unsigned short* wt = (unsigned short*)(ws + 32u * 1024 * 1024);  // 4 x 512KB

  wprep<<<dim3(8, 8, 4), 256, 0, stream>>>(Wq, Wk, Wv, Wo, wt);
  qkv_gemm<<<dim3(64, 4, 3), 256, 0, stream>>>(queries, keys, values, wt, bq, bk, bv,
                                               q_ws, k_ws, vt_ws);
  attn_kernel<<<dim3(32, 128), 256, 0, stream>>>(q_ws, k_ws, vt_ws, box, ext, hidden);
  out_gemm<<<dim3(64, 4), 256, 0, stream>>>(hidden, wt + 3u * 512 * 512, bo, out);
}

// Round 6
// 157.365 us; speedup vs baseline: 1.1213x; 1.1213x over previous
//
#include <hip/hip_runtime.h>
#include <hip/hip_bf16.h>

#define NB 16
#define NN 512
#define ND 512
#define NH 8

using short8 = __attribute__((ext_vector_type(8))) short;
using f32x4  = __attribute__((ext_vector_type(4))) float;

static __device__ __forceinline__ unsigned short f2bf(float f) {
  unsigned u = __builtin_bit_cast(unsigned, f);
  unsigned r = 0x7fffu + ((u >> 16) & 1u);
  return (unsigned short)((u + r) >> 16);
}
static __device__ __forceinline__ float bf2f(unsigned short u) {
  return __builtin_bit_cast(float, (unsigned)u << 16);
}
// async global->LDS DMA, 16B per lane: dest = uniform base + lane*16
static __device__ __forceinline__ void ld_lds16(const float* g, float* l) {
  __builtin_amdgcn_global_load_lds((const __attribute__((address_space(1))) void*)g,
                                   (__attribute__((address_space(3))) void*)l, 16, 0, 0);
}

// ---------------------------------------------------------------- kernel 0
// Transpose 4 weight mats [k][n] fp32 -> [n][k] bf16 (Wq,Wk,Wv,Wo)
__global__ __launch_bounds__(256) void wprep(
    const float* __restrict__ Wq, const float* __restrict__ Wk,
    const float* __restrict__ Wv, const float* __restrict__ Wo,
    unsigned short* __restrict__ T) {
  const float* W;
  switch (blockIdx.z) {
    case 0: W = Wq; break;
    case 1: W = Wk; break;
    case 2: W = Wv; break;
    default: W = Wo; break;
  }
  unsigned short* Wt = T + (size_t)blockIdx.z * 512 * 512;
  __shared__ float tile[64][65];
  const int t = threadIdx.x;
  const int k0 = blockIdx.x * 64, n0 = blockIdx.y * 64;
#pragma unroll
  for (int it = 0; it < 4; ++it) {
    int row = it * 16 + (t >> 4);
    int c4 = (t & 15) * 4;
    float4 v = *(const float4*)&W[(size_t)(k0 + row) * 512 + n0 + c4];
    tile[row][c4] = v.x; tile[row][c4 + 1] = v.y;
    tile[row][c4 + 2] = v.z; tile[row][c4 + 3] = v.w;
  }
  __syncthreads();
#pragma unroll
  for (int it = 0; it < 4; ++it) {
    int nr = it * 16 + (t >> 4);
    int k4 = (t & 15) * 4;
    ushort4 o;
    o.x = f2bf(tile[k4 + 0][nr]); o.y = f2bf(tile[k4 + 1][nr]);
    o.z = f2bf(tile[k4 + 2][nr]); o.w = f2bf(tile[k4 + 3][nr]);
    *(ushort4*)&Wt[(size_t)(n0 + nr) * 512 + k0 + k4] = o;
  }
}

// ---------------------------------------------------------------- kernel 1
// QKV projection: X[8192x512]fp32 @ Wt^T + b -> bf16, scattered to
// q_ws/k_ws [B,H,N,64], vt_ws [B,H,64,N]
__global__ __launch_bounds__(256) void qkv_gemm(
    const float* __restrict__ Xq, const float* __restrict__ Xk,
    const float* __restrict__ Xv, const unsigned short* __restrict__ Wt,
    const float* __restrict__ bq, const float* __restrict__ bk,
    const float* __restrict__ bv, unsigned short* __restrict__ q_ws,
    unsigned short* __restrict__ k_ws, unsigned short* __restrict__ vt_ws) {
  const int zi = blockIdx.z;
  const float* X = (zi == 0) ? Xq : (zi == 1) ? Xk : Xv;
  const unsigned short* Wz = Wt + (size_t)zi * 512 * 512;
  const float* bias = (zi == 0) ? bq : (zi == 1) ? bk : bv;
  const int m0 = blockIdx.x * 128, n0 = blockIdx.y * 128;
  __shared__ unsigned short Al[2][128][40];
  __shared__ unsigned short Bl[2][128][40];
  const int t = threadIdx.x;
  const int w = t >> 6, l = t & 63;
  const int lr = l & 15, lg = l >> 4;
  const int wr = (w >> 1) * 64, wc = (w & 1) * 64;
  f32x4 acc[4][4] = {};
  for (int kk = 0; kk < 512; kk += 64) {
    __syncthreads();
    {
      const int colk = (t & 15) * 4;
      const int kc = colk >> 5, kin = colk & 31;
#pragma unroll
      for (int p = 0; p < 8; ++p) {
        int row = p * 16 + (t >> 4);
        float4 v = *(const float4*)&X[(size_t)(m0 + row) * 512 + kk + colk];
        ushort4 o;
        o.x = f2bf(v.x); o.y = f2bf(v.y); o.z = f2bf(v.z); o.w = f2bf(v.w);
        *(ushort4*)&Al[kc][row][kin] = o;
      }
      const int colk8 = (t & 7) * 8;
      const int kc2 = colk8 >> 5, kin2 = colk8 & 31;
#pragma unroll
      for (int p = 0; p < 4; ++p) {
        int row = p * 32 + (t >> 3);
        short8 v = *(const short8*)&Wz[(size_t)(n0 + row) * 512 + kk + colk8];
        *(short8*)&Bl[kc2][row][kin2] = v;
      }
    }
    __syncthreads();
#pragma unroll
    for (int kc = 0; kc < 2; ++kc) {
      short8 a[4], b[4];
      const int lk = lg * 8;
#pragma unroll
      for (int i = 0; i < 4; ++i) a[i] = *(const short8*)&Al[kc][wr + i * 16 + lr][lk];
#pragma unroll
      for (int i = 0; i < 4; ++i) b[i] = *(const short8*)&Bl[kc][wc + i * 16 + lr][lk];
#pragma unroll
      for (int i = 0; i < 4; ++i)
#pragma unroll
        for (int j = 0; j < 4; ++j)
          acc[i][j] = __builtin_amdgcn_mfma_f32_16x16x32_bf16(a[i], b[j], acc[i][j], 0, 0, 0);
    }
  }
#pragma unroll
  for (int j = 0; j < 4; ++j) {
    const int col = n0 + wc + j * 16 + lr;
    const float bb = bias[col];
    const int hh = col >> 6, dv = col & 63;
#pragma unroll
    for (int i = 0; i < 4; ++i) {
      const int mbase = m0 + wr + i * 16 + lg * 4;
      const int b_ = mbase >> 9, nt = mbase & 511;
      if (zi == 2) {
        ushort4 o;
        o.x = f2bf(acc[i][j][0] + bb); o.y = f2bf(acc[i][j][1] + bb);
        o.z = f2bf(acc[i][j][2] + bb); o.w = f2bf(acc[i][j][3] + bb);
        *(ushort4*)&vt_ws[((size_t)(b_ * NH + hh) * 64 + dv) * 512 + nt] = o;
      } else {
        unsigned short* dst = (zi == 0) ? q_ws : k_ws;
#pragma unroll
        for (int r = 0; r < 4; ++r)
          dst[((size_t)(b_ * NH + hh) * 512 + nt + r) * 64 + dv] = f2bf(acc[i][j][r] + bb);
      }
    }
  }
}

// ---------------------------------------------------------------- kernel 2
// Attention v6 — DMA-staged box/Ext:
//   16 q-rows/block, 4 waves x 128 keys. kf preloaded to regs (issued FIRST
//   so vmcnt retires them before the stages), then 8x1KB global_load_lds of
//   box with inverse-XOR-swizzled global source + linear LDS dest (G21);
//   QK^T overlaps the DMA; vmcnt(0); pass1 reads box from LDS (2-way, free).
//   Ext staged into the same buffer during the sum1 phase. Raw s_barrier +
//   lgkmcnt(0) (NOT __syncthreads) so barriers don't drain the DMA queue.
__global__ __launch_bounds__(256, 3) void attn_kernel(
    const unsigned short* __restrict__ q_ws, const unsigned short* __restrict__ k_ws,
    const unsigned short* __restrict__ vt_ws, const float* __restrict__ box,
    const float* __restrict__ Ext, unsigned short* __restrict__ hidden) {
  const int t = threadIdx.x;
  const int w = t >> 6, l = t & 63;
  const int lr = l & 15, lg = l >> 4;
  const int bh = blockIdx.y;
  const int q0 = blockIdx.x * 16;
  const int b = bh >> 3, h = bh & 7;

  const unsigned short* Qp = q_ws + (size_t)bh * 512 * 64;
  const unsigned short* Kp = k_ws + (size_t)bh * 512 * 64;
  const unsigned short* Vt = vt_ws + (size_t)bh * 64 * 512;
  const float* boxp = box + ((size_t)bh * 512 + q0) * 512;
  const float* Ep = Ext + ((size_t)bh * 512 + q0) * 512;

  __shared__ float stg[4][2048];               // 8KB/wave staging (box, then Ext)
  __shared__ unsigned short Pt[4][16][144];    // P bf16, stride 144 (16B-aligned)
  __shared__ float red[4][16];
  __shared__ float red2[4][16];

  const int n0w = w * 128;
  float* wst = stg[w];
  unsigned short(*Pw)[144] = Pt[w];

  // Q fragments (B operand), rows q0+lr
  short8 qf0 = *(const short8*)&Qp[(size_t)(q0 + lr) * 64 + lg * 8];
  short8 qf1 = *(const short8*)&Qp[(size_t)(q0 + lr) * 64 + 32 + lg * 8];
  // kf preload: 16 loads issued BEFORE the DMA stages (vmcnt retires in
  // issue order, so MFMA's kf waits don't force the stages to drain)
  short8 kf[8][2];
#pragma unroll
  for (int c = 0; c < 8; ++c) {
    const int krow = n0w + c * 16 + lr;
    kf[c][0] = *(const short8*)&Kp[(size_t)krow * 64 + lg * 8];
    kf[c][1] = *(const short8*)&Kp[(size_t)krow * 64 + 32 + lg * 8];
  }
  // box DMA: linear LDS dest, inverse-swizzled global source.
  // LDS holds element[row][slot^(row&7)] at [row][slot] (16B granules).
#pragma unroll
  for (int it = 0; it < 8; ++it) {
    const int row2 = it * 2 + (l >> 5);
    const int slot = (l & 31) ^ (row2 & 7);
    ld_lds16(&boxp[(size_t)row2 * 512 + n0w + slot * 4], &wst[it * 256]);
  }
  __builtin_amdgcn_sched_barrier(0);

  // ---- QK^T from registers (overlaps the box DMA) ----
  f32x4 z[8];
#pragma unroll
  for (int c = 0; c < 8; ++c) {
    f32x4 a = {0.f, 0.f, 0.f, 0.f};
    a = __builtin_amdgcn_mfma_f32_16x16x32_bf16(kf[c][0], qf0, a, 0, 0, 0);
    a = __builtin_amdgcn_mfma_f32_16x16x32_bf16(kf[c][1], qf1, a, 0, 0, 0);
    z[c] = a;
  }
  asm volatile("s_waitcnt vmcnt(0)" ::: "memory");

  // ---- pass1: e1 = clip(box)*exp(att/8) -> bf16 P; row sum ----
  float s1 = 0.f;
#pragma unroll
  for (int c = 0; c < 8; ++c) {
    f32x4 bx4 = *(const f32x4*)&wst[lr * 128 + (((c * 4 + lg) ^ (lr & 7)) << 2)];
    ushort4 o;
    float e0 = fmaxf(bx4[0], 1e-6f) * __expf(z[c][0] * 0.125f);
    float e1 = fmaxf(bx4[1], 1e-6f) * __expf(z[c][1] * 0.125f);
    float e2 = fmaxf(bx4[2], 1e-6f) * __expf(z[c][2] * 0.125f);
    float e3 = fmaxf(bx4[3], 1e-6f) * __expf(z[c][3] * 0.125f);
    s1 += (e0 + e1) + (e2 + e3);
    o.x = f2bf(e0); o.y = f2bf(e1); o.z = f2bf(e2); o.w = f2bf(e3);
    *(ushort4*)&Pw[lr][c * 16 + lg * 4] = o;
  }
  // box LDS reads retired before overwriting the buffer with Ext
  asm volatile("s_waitcnt lgkmcnt(0)" ::: "memory");
#pragma unroll
  for (int it = 0; it < 8; ++it) {
    const int row2 = it * 2 + (l >> 5);
    const int slot = (l & 31) ^ (row2 & 7);
    ld_lds16(&Ep[(size_t)row2 * 512 + n0w + slot * 4], &wst[it * 256]);
  }
  __builtin_amdgcn_sched_barrier(0);
  s1 += __shfl_xor(s1, 16);
  s1 += __shfl_xor(s1, 32);
  if (lg == 0) red[w][lr] = s1;
  // raw barrier: drain LDS only, keep the Ext DMA in flight
  asm volatile("s_waitcnt lgkmcnt(0)" ::: "memory");
  __builtin_amdgcn_s_barrier();
  const float l1i = 1.0f / (red[0][lr] + red[1][lr] + red[2][lr] + red[3][lr]);
  asm volatile("s_waitcnt vmcnt(0)" ::: "memory");

  // ---- pass2: P = exp(e1*l1i + Ext), unnormalized bf16 back to LDS ----
  float s2 = 0.f;
#pragma unroll
  for (int c = 0; c < 8; ++c) {
    f32x4 ex4 = *(const f32x4*)&wst[lr * 128 + (((c * 4 + lg) ^ (lr & 7)) << 2)];
    ushort4 u = *(const ushort4*)&Pw[lr][c * 16 + lg * 4];
    ushort4 o;
    float e0 = __expf(bf2f(u.x) * l1i + ex4[0]);
    float e1 = __expf(bf2f(u.y) * l1i + ex4[1]);
    float e2 = __expf(bf2f(u.z) * l1i + ex4[2]);
    float e3 = __expf(bf2f(u.w) * l1i + ex4[3]);
    s2 += (e0 + e1) + (e2 + e3);
    o.x = f2bf(e0); o.y = f2bf(e1); o.z = f2bf(e2); o.w = f2bf(e3);
    *(ushort4*)&Pw[lr][c * 16 + lg * 4] = o;
  }
  s2 += __shfl_xor(s2, 16);
  s2 += __shfl_xor(s2, 32);
  if (lg == 0) red2[w][lr] = s2;
  asm volatile("s_waitcnt lgkmcnt(0)" ::: "memory");
  __builtin_amdgcn_s_barrier();

  // ---- PV: wave's partial over its 128 keys (P unnormalized) ----
  f32x4 o4[4] = {};
#pragma unroll
  for (int kc = 0; kc < 4; ++kc) {
    short8 pa = *(const short8*)&Pw[lr][kc * 32 + lg * 8];
#pragma unroll
    for (int c2 = 0; c2 < 4; ++c2) {
      short8 vf = *(const short8*)&Vt[(size_t)(c2 * 16 + lr) * 512 + n0w + kc * 32 + lg * 8];
      o4[c2] = __builtin_amdgcn_mfma_f32_16x16x32_bf16(pa, vf, o4[c2], 0, 0, 0);
    }
  }
  // l2 inverses for this thread's output rows (m = lg*4+r)
  f32x4 rs = *(const f32x4*)&red2[0][lg * 4];
#pragma unroll
  for (int w2 = 1; w2 < 4; ++w2) {
    f32x4 p = *(const f32x4*)&red2[w2][lg * 4];
#pragma unroll
    for (int r = 0; r < 4; ++r) rs[r] += p[r];
  }
  f32x4 l2v;
#pragma unroll
  for (int r = 0; r < 4; ++r) l2v[r] = 1.0f / rs[r];
  // partial out (normalized) -> own region (aliases own P tile)
  float* ow = (float*)Pw;
#pragma unroll
  for (int c2 = 0; c2 < 4; ++c2)
#pragma unroll
    for (int r = 0; r < 4; ++r)
      ow[(lg * 4 + r) * 68 + c2 * 16 + lr] = o4[c2][r] * l2v[r];
  asm volatile("s_waitcnt lgkmcnt(0)" ::: "memory");
  __builtin_amdgcn_s_barrier();
  // cross-wave sum + vectorized store (ushort4)
  {
    const int lrow = t >> 4;
    const int d4 = (t & 15) * 4;
    f32x4 s = *(const f32x4*)&((const float*)Pt[0])[lrow * 68 + d4];
#pragma unroll
    for (int w2 = 1; w2 < 4; ++w2) {
      f32x4 p = *(const f32x4*)&((const float*)Pt[w2])[lrow * 68 + d4];
#pragma unroll
      for (int r = 0; r < 4; ++r) s[r] += p[r];
    }
    ushort4 oo;
    oo.x = f2bf(s[0]); oo.y = f2bf(s[1]); oo.z = f2bf(s[2]); oo.w = f2bf(s[3]);
    *(ushort4*)&hidden[(size_t)(b * 512 + q0 + lrow) * 512 + h * 64 + d4] = oo;
  }
}

// ---------------------------------------------------------------- kernel 3
// out = hidden[8192x512]bf16 @ WoT + bo  (fp32 out)
__global__ __launch_bounds__(256) void out_gemm(
    const unsigned short* __restrict__ hidden, const unsigned short* __restrict__ WoT,
    const float* __restrict__ bo, float* __restrict__ out) {
  const int m0 = blockIdx.x * 128, n0 = blockIdx.y * 128;
  __shared__ unsigned short Al[2][128][40];
  __shared__ unsigned short Bl[2][128][40];
  const int t = threadIdx.x;
  const int w = t >> 6, l = t & 63;
  const int lr = l & 15, lg = l >> 4;
  const int wr = (w >> 1) * 64, wc = (w & 1) * 64;
  f32x4 acc[4][4] = {};
  for (int kk = 0; kk < 512; kk += 64) {
    __syncthreads();
    {
      const int colk8 = (t & 7) * 8;
      const int kc2 = colk8 >> 5, kin2 = colk8 & 31;
#pragma unroll
      for (int p = 0; p < 4; ++p) {
        int row = p * 32 + (t >> 3);
        short8 v = *(const short8*)&hidden[(size_t)(m0 + row) * 512 + kk + colk8];
        *(short8*)&Al[kc2][row][kin2] = v;
      }
#pragma unroll
      for (int p = 0; p < 4; ++p) {
        int row = p * 32 + (t >> 3);
        short8 v = *(const short8*)&WoT[(size_t)(n0 + row) * 512 + kk + colk8];
        *(short8*)&Bl[kc2][row][kin2] = v;
      }
    }
    __syncthreads();
#pragma unroll
    for (int kc = 0; kc < 2; ++kc) {
      short8 a[4], b[4];
      const int lk = lg * 8;
#pragma unroll
      for (int i = 0; i < 4; ++i) a[i] = *(const short8*)&Al[kc][wr + i * 16 + lr][lk];
#pragma unroll
      for (int i = 0; i < 4; ++i) b[i] = *(const short8*)&Bl[kc][wc + i * 16 + lr][lk];
#pragma unroll
      for (int i = 0; i < 4; ++i)
#pragma unroll
        for (int j = 0; j < 4; ++j)
          acc[i][j] = __builtin_amdgcn_mfma_f32_16x16x32_bf16(a[i], b[j], acc[i][j], 0, 0, 0);
    }
  }
#pragma unroll
  for (int j = 0; j < 4; ++j) {
    const int col = n0 + wc + j * 16 + lr;
    const float bb = bo[col];
#pragma unroll
    for (int i = 0; i < 4; ++i)
#pragma unroll
      for (int r = 0; r < 4; ++r)
        out[(size_t)(m0 + wr + i * 16 + lg * 4 + r) * 512 + col] = acc[i][j][r] + bb;
  }
}

// ---------------------------------------------------------------- launch
extern "C" void kernel_launch(void* const* d_in, const int* in_sizes, int n_in,
                              void* d_out, int out_size, void* d_ws, size_t ws_size,
                              hipStream_t stream) {
  const float* queries = (const float*)d_in[0];
  const float* keys = (const float*)d_in[1];
  const float* values = (const float*)d_in[2];
  const float* box = (const float*)d_in[3];
  const float* ext = (const float*)d_in[4];
  const float* Wq = (const float*)d_in[5];
  const float* bq = (const float*)d_in[6];
  const float* Wk = (const float*)d_in[7];
  const float* bk = (const float*)d_in[8];
  const float* Wv = (const float*)d_in[9];
  const float* bv = (const float*)d_in[10];
  const float* Wo = (const float*)d_in[11];
  const float* bo = (const float*)d_in[12];
  float* out = (float*)d_out;

  char* ws = (char*)d_ws;
  unsigned short* q_ws = (unsigned short*)(ws);
  unsigned short* k_ws = (unsigned short*)(ws + 8u * 1024 * 1024);
  unsigned short* vt_ws = (unsigned short*)(ws + 16u * 1024 * 1024);
  unsigned short* hidden = (unsigned short*)(ws + 24u * 1024 * 1024);
  unsigned short* wt = (unsigned short*)(ws + 32u * 1024 * 1024);  // 4 x 512KB

  wprep<<<dim3(8, 8, 4), 256, 0, stream>>>(Wq, Wk, Wv, Wo, wt);
  qkv_gemm<<<dim3(64, 4, 3), 256, 0, stream>>>(queries, keys, values, wt, bq, bk, bv,
                                               q_ws, k_ws, vt_ws);
  attn_kernel<<<dim3(32, 128), 256, 0, stream>>>(q_ws, k_ws, vt_ws, box, ext, hidden);
  out_gemm<<<dim3(64, 4), 256, 0, stream>>>(hidden, wt + 3u * 512 * 512, bo, out);
}